// Round 16
// baseline (251.799 us; speedup 1.0000x reference)
//
#include <hip/hip_runtime.h>

#define NGRAPH 256
#define NNODE  1000
#define NEDGE  16000
#define DIM    32
#define HSU    40   // packed h row stride in USHORTS (80B: 16B-aligned, 8 bank-start groups)

typedef __attribute__((ext_vector_type(2))) float f2;

__device__ __forceinline__ f2 mkf2(float a, float b) { f2 r; r.x = a; r.y = b; return r; }

__device__ __forceinline__ unsigned monof(float f) {
  unsigned b = __float_as_uint(f);
  return (b & 0x80000000u) ? ~b : (b | 0x80000000u);
}

__device__ __forceinline__ f2 f2max(f2 a, f2 b) { return mkf2(fmaxf(a.x,b.x), fmaxf(a.y,b.y)); }
__device__ __forceinline__ f2 shfl2(f2 v, int m) {
  return mkf2(__shfl_xor(v.x,m,64), __shfl_xor(v.y,m,64));
}

struct __align__(16) Smem {
  union { unsigned short h[NNODE * HSU]; unsigned stage[NEDGE]; } hu;  // 80000 B
  unsigned short csr[NEDGE];      // 32000 (orig-dst buckets, built once)
  unsigned rowStart[1004];        // 4016
  unsigned cnt[1024];             // 4096 (build only)
  unsigned histA[257];            // 1028
  unsigned histB[257];            // 1028
  unsigned wsum[16];              // 64
  float redm[512];                // 2048
  float reds[512];                // 2048
  float eacc[64];                 // 256
  float hbuf[48];                 // 192  => ~127 KB total
};

// exclusive block scan over 1024 threads; leaves total in wsum[15]
__device__ __forceinline__ unsigned blockExclScan(unsigned v, unsigned* wsum, int tid) {
  __syncthreads();
  int lane = tid & 63, w = tid >> 6;
  unsigned x = v;
  #pragma unroll
  for (int d = 1; d < 64; d <<= 1) {
    unsigned t = __shfl_up(x, d, 64);
    if (lane >= d) x += t;
  }
  if (lane == 63) wsum[w] = x;
  __syncthreads();
  if (w == 0) {
    unsigned s = (lane < 16) ? wsum[lane] : 0u;
    #pragma unroll
    for (int d = 1; d < 16; d <<= 1) {
      unsigned t = __shfl_up(s, d, 64);
      if (lane >= d) s += t;
    }
    if (lane < 16) wsum[lane] = s;
  }
  __syncthreads();
  unsigned base = (w > 0) ? wsum[w - 1] : 0u;
  return base + x - v;
}

// ---- bf16 pack / packed-max / expand-to-f2 ----
#define CVTB(d, lo, hi) asm("v_cvt_pk_bf16_f32 %0, %1, %2" : "=v"(d) : "v"(lo), "v"(hi))
#define CVTQ(q, t0, t1) CVTB(q.x,t0.x,t0.y); CVTB(q.y,t0.z,t0.w); CVTB(q.z,t1.x,t1.y); CVTB(q.w,t1.z,t1.w)
#define PKM(a, b) asm("v_pk_max_u16 %0, %0, %1" : "+v"(a) : "v"(b))
#define EXF2(e, u) e = mkf2(__uint_as_float((u) << 16), __uint_as_float((u) & 0xFFFF0000u))

// ---- packed-f32 dot machinery: acc += w*x contracts to v_pk_fma_f32 ----
#define PKFMA(acc, w_, xv) (acc) += (w_) * (xv)
// dot of a 32-float weight row (as 16 f2 words at (R)*(S2)+(O2)) against x0..x15
#define XDOTPK(W2, R, S2, O2) __extension__({ f2 ac_ = mkf2(0.f,0.f); \
  PKFMA(ac_,(W2)[(R)*(S2)+(O2)+ 0],x0);  PKFMA(ac_,(W2)[(R)*(S2)+(O2)+ 1],x1); \
  PKFMA(ac_,(W2)[(R)*(S2)+(O2)+ 2],x2);  PKFMA(ac_,(W2)[(R)*(S2)+(O2)+ 3],x3); \
  PKFMA(ac_,(W2)[(R)*(S2)+(O2)+ 4],x4);  PKFMA(ac_,(W2)[(R)*(S2)+(O2)+ 5],x5); \
  PKFMA(ac_,(W2)[(R)*(S2)+(O2)+ 6],x6);  PKFMA(ac_,(W2)[(R)*(S2)+(O2)+ 7],x7); \
  PKFMA(ac_,(W2)[(R)*(S2)+(O2)+ 8],x8);  PKFMA(ac_,(W2)[(R)*(S2)+(O2)+ 9],x9); \
  PKFMA(ac_,(W2)[(R)*(S2)+(O2)+10],x10); PKFMA(ac_,(W2)[(R)*(S2)+(O2)+11],x11); \
  PKFMA(ac_,(W2)[(R)*(S2)+(O2)+12],x12); PKFMA(ac_,(W2)[(R)*(S2)+(O2)+13],x13); \
  PKFMA(ac_,(W2)[(R)*(S2)+(O2)+14],x14); PKFMA(ac_,(W2)[(R)*(S2)+(O2)+15],x15); \
  ac_.x + ac_.y; })
// dot of a 16-float U half-row (8 f2 words at R*32+O2) against he0..he7
#define GDOTPK(R, O2) __extension__({ f2 ac_ = mkf2(0.f,0.f); \
  PKFMA(ac_,U2[(R)*32+(O2)+0],he0); PKFMA(ac_,U2[(R)*32+(O2)+1],he1); \
  PKFMA(ac_,U2[(R)*32+(O2)+2],he2); PKFMA(ac_,U2[(R)*32+(O2)+3],he3); \
  PKFMA(ac_,U2[(R)*32+(O2)+4],he4); PKFMA(ac_,U2[(R)*32+(O2)+5],he5); \
  PKFMA(ac_,U2[(R)*32+(O2)+6],he6); PKFMA(ac_,U2[(R)*32+(O2)+7],he7); \
  ac_.x + ac_.y; })
#define ACC4(v, R)       v.x  = XDOTPK(U2,(R),32,16); v.y  = XDOTPK(U2,(R)+1,32,16); \
                         v.z  = XDOTPK(U2,(R)+2,32,16); v.w  = XDOTPK(U2,(R)+3,32,16);
#define ACC4ADD(v, R, O2) v.x += GDOTPK((R),(O2)); v.y += GDOTPK((R)+1,(O2)); \
                          v.z += GDOTPK((R)+2,(O2)); v.w += GDOTPK((R)+3,(O2));
#define HV4(v, R)  v.x = fmaxf(Bv[(R)]+XDOTPK(W2,(R),16,0),0.f); v.y = fmaxf(Bv[(R)+1]+XDOTPK(W2,(R)+1,16,0),0.f); \
                   v.z = fmaxf(Bv[(R)+2]+XDOTPK(W2,(R)+2,16,0),0.f); v.w = fmaxf(Bv[(R)+3]+XDOTPK(W2,(R)+3,16,0),0.f);
#define REDCH2(v, OFF) do { \
  f2 mx = act ? (v) : mkf2(-__builtin_inff(),-__builtin_inff()); \
  f2 sv = act ? (v) : mkf2(0.f,0.f); \
  mx = f2max(mx, shfl2(mx,32)); sv += shfl2(sv,32); \
  mx = f2max(mx, shfl2(mx,16)); sv += shfl2(sv,16); \
  mx = f2max(mx, shfl2(mx, 8)); sv += shfl2(sv, 8); \
  mx = f2max(mx, shfl2(mx, 4)); sv += shfl2(sv, 4); \
  mx = f2max(mx, shfl2(mx, 2)); sv += shfl2(sv, 2); \
  mx = f2max(mx, shfl2(mx, 1)); sv += shfl2(sv, 1); \
  if (lane == 0) { *((f2*)(sm.redm + wv*32 + (OFF))) = mx; *((f2*)(sm.reds + wv*32 + (OFF))) = sv; } \
} while (0)

extern "C" __global__ void
__attribute__((amdgpu_flat_work_group_size(1024,1024)))
__attribute__((amdgpu_waves_per_eu(4,4)))
gnn_topk_kernel(const int* __restrict__ x_ids, const int* __restrict__ eidx,
                const float* __restrict__ emb,
                const float* __restrict__ w1, const float* __restrict__ b1,
                const float* __restrict__ u1, const float* __restrict__ p1,
                const float* __restrict__ w2, const float* __restrict__ b2,
                const float* __restrict__ u2, const float* __restrict__ p2,
                const float* __restrict__ w3, const float* __restrict__ b3,
                const float* __restrict__ u3, const float* __restrict__ p3,
                const float* __restrict__ l1w, const float* __restrict__ l1b,
                const float* __restrict__ l2w, const float* __restrict__ l2b,
                const float* __restrict__ l3w, const float* __restrict__ l3b,
                float* __restrict__ out)
{
  const int g = blockIdx.x;
  const int tid = (int)threadIdx.x;
  const int lane = tid & 63, wv = tid >> 6;

  __shared__ Smem sm;
  unsigned short* hb = sm.hu.h;

  const int* esrc = eidx + (size_t)g * (2 * NEDGE);
  const int* edst = esrc + NEDGE;

  // ---- init: x = emb[ids] as 16 f2 words; nodes never move between threads ----
  f2 x0,x1,x2,x3,x4,x5,x6,x7,x8,x9,x10,x11,x12,x13,x14,x15;
  bool alive = (tid < NNODE);
  if (alive) {
    int id = x_ids[(size_t)g * NNODE + tid];
    const f2* ep2 = (const f2*)(emb + (size_t)id * DIM);
    x0=ep2[0];  x1=ep2[1];  x2=ep2[2];  x3=ep2[3];
    x4=ep2[4];  x5=ep2[5];  x6=ep2[6];  x7=ep2[7];
    x8=ep2[8];  x9=ep2[9];  x10=ep2[10]; x11=ep2[11];
    x12=ep2[12]; x13=ep2[13]; x14=ep2[14]; x15=ep2[15];
  } else {
    f2 z = mkf2(0.f,0.f);
    x0=x1=x2=x3=x4=x5=x6=x7=x8=x9=x10=x11=x12=x13=x14=x15=z;
  }
  if (tid < 64) sm.eacc[tid] = 0.f;
  __syncthreads();

  #pragma unroll 1
  for (int layer = 0; layer < 3; ++layer) {
    const float* W  = (layer==0)? w1 : (layer==1)? w2 : w3;
    const float* Bv = (layer==0)? b1 : (layer==1)? b2 : b3;
    const float* U  = (layer==0)? u1 : (layer==1)? u2 : u3;
    const float* P  = (layer==0)? p1 : (layer==1)? p2 : p3;
    const int k     = (layer==0)? 800 : (layer==1)? 640 : 512;
    const f2* W2 = (const f2*)W;
    const f2* U2 = (const f2*)U;
    const f2* P2 = (const f2*)P;

    // ---- CSR build ONCE (layer 0): buckets by original dst id ----
    if (layer == 0) {
      sm.cnt[tid] = 0u;
      __syncthreads();
      for (int e = tid; e < NEDGE; e += 1024) {
        int s = esrc[e];
        int d = edst[e];
        atomicAdd(&sm.cnt[d], 1u);
        sm.hu.stage[e] = ((unsigned)d << 16) | (unsigned)s;
      }
      __syncthreads();
      unsigned cv = sm.cnt[tid];
      unsigned excl = blockExclScan(cv, sm.wsum, tid);
      unsigned total = sm.wsum[15];
      if (tid < NNODE) sm.rowStart[tid] = excl;
      if (tid == 0) sm.rowStart[NNODE] = total;
      sm.cnt[tid] = excl;              // cursor
      __syncthreads();
      for (int e = tid; e < NEDGE; e += 1024) {
        unsigned pk = sm.hu.stage[e];
        unsigned d = pk >> 16;
        unsigned pos = atomicAdd(&sm.cnt[d], 1u);
        sm.csr[pos] = (unsigned short)(pk & 0xFFFFu);
      }
      __syncthreads();   // stage consumed; h region reusable
    }

    unsigned wbeg = 0, wend = 0;
    if (tid < NNODE) { wbeg = sm.rowStart[tid]; wend = sm.rowStart[tid + 1]; }

    uint4* hq = (uint4*)(hb + tid * HSU);

    // ---- phase 1: full h = relu(W@x+b), packed bf16 -> own row; then a = U2@x ----
    float4 a0,a1,a2,a3,a4,a5,a6,a7;
    if (tid < NNODE) {
      if (alive) {
        float4 t0, t1; uint4 q;
        HV4(t0,0)  HV4(t1,4)  CVTQ(q,t0,t1); hq[0]=q;
        HV4(t0,8)  HV4(t1,12) CVTQ(q,t0,t1); hq[1]=q;
        HV4(t0,16) HV4(t1,20) CVTQ(q,t0,t1); hq[2]=q;
        HV4(t0,24) HV4(t1,28) CVTQ(q,t0,t1); hq[3]=q;
      } else {
        uint4 z = make_uint4(0,0,0,0);   // bf16 zeros: max-neutral (h >= 0)
        hq[0]=z; hq[1]=z; hq[2]=z; hq[3]=z;
      }
    }
    if (alive) {
      ACC4(a0,0) ACC4(a1,4) ACC4(a2,8) ACC4(a3,12)
      ACC4(a4,16) ACC4(a5,20) ACC4(a6,24) ACC4(a7,28)
    }
    __syncthreads();   // all packed rows visible; x dead from here

    // ---- single walk: packed u16-max over all 32 features (branch-free) ----
    if (alive) {
      uint4 g0 = hq[0], g1 = hq[1], g2 = hq[2], g3 = hq[3];   // self-loop init
      for (unsigned e = wbeg; e < wend; ++e) {
        const uint4* rp = (const uint4*)(hb + sm.csr[e] * HSU);
        uint4 v0 = rp[0], v1 = rp[1], v2 = rp[2], v3 = rp[3];
        PKM(g0.x,v0.x); PKM(g0.y,v0.y); PKM(g0.z,v0.z); PKM(g0.w,v0.w);
        PKM(g1.x,v1.x); PKM(g1.y,v1.y); PKM(g1.z,v1.z); PKM(g1.w,v1.w);
        PKM(g2.x,v2.x); PKM(g2.y,v2.y); PKM(g2.z,v2.z); PKM(g2.w,v2.w);
        PKM(g3.x,v3.x); PKM(g3.y,v3.y); PKM(g3.z,v3.z); PKM(g3.w,v3.w);
      }
      f2 he0,he1,he2,he3,he4,he5,he6,he7;
      EXF2(he0,g0.x); EXF2(he1,g0.y); EXF2(he2,g0.z); EXF2(he3,g0.w);
      EXF2(he4,g1.x); EXF2(he5,g1.y); EXF2(he6,g1.z); EXF2(he7,g1.w);
      ACC4ADD(a0,0,0) ACC4ADD(a1,4,0) ACC4ADD(a2,8,0) ACC4ADD(a3,12,0)
      ACC4ADD(a4,16,0) ACC4ADD(a5,20,0) ACC4ADD(a6,24,0) ACC4ADD(a7,28,0)
      EXF2(he0,g2.x); EXF2(he1,g2.y); EXF2(he2,g2.z); EXF2(he3,g2.w);
      EXF2(he4,g3.x); EXF2(he5,g3.y); EXF2(he6,g3.z); EXF2(he7,g3.w);
      ACC4ADD(a0,0,8) ACC4ADD(a1,4,8) ACC4ADD(a2,8,8) ACC4ADD(a3,12,8)
      ACC4ADD(a4,16,8) ACC4ADD(a5,20,8) ACC4ADD(a6,24,8) ACC4ADD(a7,28,8)
      x0  = mkf2(fmaxf(a0.x,0.f), fmaxf(a0.y,0.f));
      x1  = mkf2(fmaxf(a0.z,0.f), fmaxf(a0.w,0.f));
      x2  = mkf2(fmaxf(a1.x,0.f), fmaxf(a1.y,0.f));
      x3  = mkf2(fmaxf(a1.z,0.f), fmaxf(a1.w,0.f));
      x4  = mkf2(fmaxf(a2.x,0.f), fmaxf(a2.y,0.f));
      x5  = mkf2(fmaxf(a2.z,0.f), fmaxf(a2.w,0.f));
      x6  = mkf2(fmaxf(a3.x,0.f), fmaxf(a3.y,0.f));
      x7  = mkf2(fmaxf(a3.z,0.f), fmaxf(a3.w,0.f));
      x8  = mkf2(fmaxf(a4.x,0.f), fmaxf(a4.y,0.f));
      x9  = mkf2(fmaxf(a4.z,0.f), fmaxf(a4.w,0.f));
      x10 = mkf2(fmaxf(a5.x,0.f), fmaxf(a5.y,0.f));
      x11 = mkf2(fmaxf(a5.z,0.f), fmaxf(a5.w,0.f));
      x12 = mkf2(fmaxf(a6.x,0.f), fmaxf(a6.y,0.f));
      x13 = mkf2(fmaxf(a6.z,0.f), fmaxf(a6.w,0.f));
      x14 = mkf2(fmaxf(a7.x,0.f), fmaxf(a7.y,0.f));
      x15 = mkf2(fmaxf(a7.z,0.f), fmaxf(a7.w,0.f));
    }

    // ---- pool: score = tanh(x.p/||p||) (kept in register) ----
    float pn = 0.f;
    for (int c = 0; c < DIM; ++c) pn += P[c] * P[c];
    pn = sqrtf(pn);
    unsigned key = 0xFFFFFFFFu;
    float val = 0.f;
    if (alive) {
      float dp = XDOTPK(P2, 0, 16, 0);
      val = tanhf(dp / pn);
      key = ~monof(val);   // ascending key == descending score
    }
    for (int i = tid; i < 257; i += 1024) { sm.histA[i] = 0u; sm.histB[i] = 0u; }
    __syncthreads();   // all walk reads complete before rows rewritten next layer

    // ---- exact top-k: 4-pass radix select, ping-pong histograms ----
    bool cand = alive;
    bool sel = false;
    unsigned target = (unsigned)k;
    unsigned dig = (key >> 24) & 255u;
    if (cand) atomicAdd(&sm.histA[dig], 1u);
    __syncthreads();
    #pragma unroll 1
    for (int p = 0; p < 4; ++p) {
      unsigned* buf  = (p & 1) ? sm.histB : sm.histA;
      unsigned* nbuf = (p & 1) ? sm.histA : sm.histB;
      if (tid < 64) {   // wave0: exclusive scan of 256 bins
        unsigned q0 = buf[tid*4], q1 = buf[tid*4+1], q2 = buf[tid*4+2], q3 = buf[tid*4+3];
        unsigned s1 = q0+q1, s2v = s1+q2, s3 = s2v+q3;
        unsigned tot = s3;
        #pragma unroll
        for (int d = 1; d < 64; d <<= 1) {
          unsigned t = __shfl_up(tot, d, 64);
          if (lane >= d) tot += t;
        }
        unsigned base = tot - s3;
        buf[tid*4] = base; buf[tid*4+1] = base+q0; buf[tid*4+2] = base+s1; buf[tid*4+3] = base+s2v;
        if (tid == 63) buf[256] = tot;
      } else if (p > 0 && p < 3) {
        for (int i = tid - 64; i < 257; i += 960) nbuf[i] = 0u;
      }
      __syncthreads();
      if (cand) {
        unsigned lo = buf[dig], hi = buf[dig+1];
        if (hi <= target)      { sel = true;  cand = false; }
        else if (lo >= target) { cand = false; }
        else                   { target -= lo; }
      }
      if (p < 3) {
        dig = (key >> (16 - 8*p)) & 255u;
        if (cand) atomicAdd(&nbuf[dig], 1u);
      }
      __syncthreads();
    }
    // tie resolution: ballot-based rank (smallest original tid wins)
    {
      unsigned long long bm = __ballot(cand);
      if (lane == 0) sm.wsum[wv] = (unsigned)__popcll(bm);
      __syncthreads();
      unsigned pre = 0;
      for (int w_ = 0; w_ < wv; ++w_) pre += sm.wsum[w_];
      unsigned trank = pre + (unsigned)__popcll(bm & ((1ULL << lane) - 1ULL));
      if (cand && trank < target) sel = true;
    }

    // ---- select-in-place ----
    alive = sel;
    if (sel) {
      x0*=val; x1*=val; x2*=val; x3*=val; x4*=val; x5*=val; x6*=val; x7*=val;
      x8*=val; x9*=val; x10*=val; x11*=val; x12*=val; x13*=val; x14*=val; x15*=val;
    } else {
      f2 z = mkf2(0.f,0.f);
      x0=x1=x2=x3=x4=x5=x6=x7=x8=x9=x10=x11=x12=x13=x14=x15=z;
    }

    // ---- readout: gmp || gap over survivors ----
    {
      bool act = alive;
      REDCH2(x0, 0);  REDCH2(x1, 2);  REDCH2(x2, 4);  REDCH2(x3, 6);
      REDCH2(x4, 8);  REDCH2(x5,10);  REDCH2(x6,12);  REDCH2(x7,14);
      REDCH2(x8,16);  REDCH2(x9,18);  REDCH2(x10,20); REDCH2(x11,22);
      REDCH2(x12,24); REDCH2(x13,26); REDCH2(x14,28); REDCH2(x15,30);
    }
    __syncthreads();
    if (tid < 32) {
      float rm = -__builtin_inff(), rs = 0.f;
      #pragma unroll
      for (int w_ = 0; w_ < 16; ++w_) {
        rm = fmaxf(rm, sm.redm[w_*32 + tid]);
        rs += sm.reds[w_*32 + tid];
      }
      sm.eacc[tid] += rm;
      sm.eacc[32 + tid] += rs / (float)k;
    }
    __syncthreads();
  }

  // ---- MLP head ----
  if (tid < 32) {
    float v = l1b[tid];
    #pragma unroll
    for (int c = 0; c < 64; ++c) v += l1w[tid*64 + c] * sm.eacc[c];
    sm.hbuf[tid] = fmaxf(v, 0.f);
  }
  __syncthreads();
  if (tid < 16) {
    float v = l2b[tid];
    #pragma unroll
    for (int c = 0; c < 32; ++c) v += l2w[tid*32 + c] * sm.hbuf[c];
    sm.hbuf[32 + tid] = fmaxf(v, 0.f);
  }
  __syncthreads();
  if (tid == 0) {
    float v = l3b[0];
    #pragma unroll
    for (int c = 0; c < 16; ++c) v += l3w[c] * sm.hbuf[32 + c];
    out[g] = 1.f / (1.f + expf(-v));
  }
  if (tid < 64) out[NGRAPH + (size_t)g*64 + tid] = sm.eacc[tid];
}

extern "C" void kernel_launch(void* const* d_in, const int* in_sizes, int n_in,
                              void* d_out, int out_size, void* d_ws, size_t ws_size,
                              hipStream_t stream) {
  (void)in_sizes; (void)n_in; (void)d_ws; (void)ws_size; (void)out_size;
  const int*   x_ids = (const int*)d_in[0];
  const int*   eidx  = (const int*)d_in[1];
  const float* emb   = (const float*)d_in[2];
  const float* w1 = (const float*)d_in[3],  *b1 = (const float*)d_in[4];
  const float* u1 = (const float*)d_in[5],  *p1 = (const float*)d_in[6];
  const float* w2 = (const float*)d_in[7],  *b2 = (const float*)d_in[8];
  const float* u2 = (const float*)d_in[9],  *p2 = (const float*)d_in[10];
  const float* w3 = (const float*)d_in[11], *b3 = (const float*)d_in[12];
  const float* u3 = (const float*)d_in[13], *p3 = (const float*)d_in[14];
  const float* l1w = (const float*)d_in[15], *l1b = (const float*)d_in[16];
  const float* l2w = (const float*)d_in[17], *l2b = (const float*)d_in[18];
  const float* l3w = (const float*)d_in[19], *l3b = (const float*)d_in[20];
  float* out = (float*)d_out;

  gnn_topk_kernel<<<dim3(NGRAPH), dim3(1024), 0, stream>>>(
      x_ids, eidx, emb,
      w1, b1, u1, p1, w2, b2, u2, p2, w3, b3, u3, p3,
      l1w, l1b, l2w, l2b, l3w, l3b, out);
}

// Round 17
// 214.104 us; speedup vs baseline: 1.1761x; 1.1761x over previous
//
#include <hip/hip_runtime.h>

#define NGRAPH 256
#define NNODE  1000
#define NEDGE  16000
#define DIM    32
#define HSU    40   // packed h row stride in USHORTS (80B: 16B-aligned, 8 bank-start groups)

__device__ __forceinline__ unsigned monof(float f) {
  unsigned b = __float_as_uint(f);
  return (b & 0x80000000u) ? ~b : (b | 0x80000000u);
}

__device__ __forceinline__ float4 f4max(float4 a, float4 b) {
  return make_float4(fmaxf(a.x,b.x), fmaxf(a.y,b.y), fmaxf(a.z,b.z), fmaxf(a.w,b.w));
}
__device__ __forceinline__ float4 f4relu(float4 a) {
  return make_float4(fmaxf(a.x,0.f), fmaxf(a.y,0.f), fmaxf(a.z,0.f), fmaxf(a.w,0.f));
}
__device__ __forceinline__ float4 f4scale(float4 a, float s) {
  return make_float4(a.x*s, a.y*s, a.z*s, a.w*s);
}
__device__ __forceinline__ float4 f4add(float4 a, float4 b) {
  return make_float4(a.x+b.x, a.y+b.y, a.z+b.z, a.w+b.w);
}
__device__ __forceinline__ float dot4(float4 a, float4 b) {
  return a.x*b.x + a.y*b.y + a.z*b.z + a.w*b.w;
}
__device__ __forceinline__ float4 shfl4(float4 v, int m) {
  return make_float4(__shfl_xor(v.x,m,64), __shfl_xor(v.y,m,64),
                     __shfl_xor(v.z,m,64), __shfl_xor(v.w,m,64));
}

struct __align__(16) Smem {
  union { unsigned short h[NNODE * HSU]; unsigned stage[NEDGE]; } hu;  // 80000 B
  unsigned short csr[NEDGE];      // 32000 (orig-dst buckets; compacted per layer)
  unsigned rowStart[1004];        // 4016
  unsigned cnt[1024];             // 4096 (build only)
  unsigned histA[257];            // 1028
  unsigned histB[257];            // 1028
  unsigned wsum[16];              // 64
  float redm[512];                // 2048
  float reds[512];                // 2048
  float eacc[64];                 // 256
  float hbuf[48];                 // 192
  unsigned char alv[1024];        // 1024 alive mask (for compaction)
};                                 // ~128 KB total

// exclusive block scan over 1024 threads; leaves total in wsum[15]
__device__ __forceinline__ unsigned blockExclScan(unsigned v, unsigned* wsum, int tid) {
  __syncthreads();
  int lane = tid & 63, w = tid >> 6;
  unsigned x = v;
  #pragma unroll
  for (int d = 1; d < 64; d <<= 1) {
    unsigned t = __shfl_up(x, d, 64);
    if (lane >= d) x += t;
  }
  if (lane == 63) wsum[w] = x;
  __syncthreads();
  if (w == 0) {
    unsigned s = (lane < 16) ? wsum[lane] : 0u;
    #pragma unroll
    for (int d = 1; d < 16; d <<= 1) {
      unsigned t = __shfl_up(s, d, 64);
      if (lane >= d) s += t;
    }
    if (lane < 16) wsum[lane] = s;
  }
  __syncthreads();
  unsigned base = (w > 0) ? wsum[w - 1] : 0u;
  return base + x - v;
}

// ---- bf16 pack / packed-max / expand ----
#define CVTB(d, lo, hi) asm("v_cvt_pk_bf16_f32 %0, %1, %2" : "=v"(d) : "v"(lo), "v"(hi))
#define CVTQ(q, t0, t1) CVTB(q.x,t0.x,t0.y); CVTB(q.y,t0.z,t0.w); CVTB(q.z,t1.x,t1.y); CVTB(q.w,t1.z,t1.w)
#define PKM(a, b) asm("v_pk_max_u16 %0, %0, %1" : "+v"(a) : "v"(b))
#define XLO(u) __uint_as_float((u) << 16)
#define XHI(u) __uint_as_float((u) & 0xFFFF0000u)
#define EXPAND(ha, hb_, gq) ha = make_float4(XLO((gq).x),XHI((gq).x),XLO((gq).y),XHI((gq).y)); \
                            hb_ = make_float4(XLO((gq).z),XHI((gq).z),XLO((gq).w),XHI((gq).w))

// dot of 8 float4 weight words against x0..x7 (locals in scope)
#define XDOT(P4, R, S, O) ( dot4((P4)[(R)*(S)+(O)  ], x0) + dot4((P4)[(R)*(S)+(O)+1], x1) \
                          + dot4((P4)[(R)*(S)+(O)+2], x2) + dot4((P4)[(R)*(S)+(O)+3], x3) \
                          + dot4((P4)[(R)*(S)+(O)+4], x4) + dot4((P4)[(R)*(S)+(O)+5], x5) \
                          + dot4((P4)[(R)*(S)+(O)+6], x6) + dot4((P4)[(R)*(S)+(O)+7], x7) )
// dot of 4 float4 U words against h0..h3 (expanded aggregated half)
#define GDOT(R, O) ( dot4(U4[(R)*16+(O)  ], h0) + dot4(U4[(R)*16+(O)+1], h1) \
                   + dot4(U4[(R)*16+(O)+2], h2) + dot4(U4[(R)*16+(O)+3], h3) )
#define ACC4(v, R)    v.x  = XDOT(U4,(R),16,8); v.y  = XDOT(U4,(R)+1,16,8); v.z  = XDOT(U4,(R)+2,16,8); v.w  = XDOT(U4,(R)+3,16,8);
#define ACC4ADD(v, R, O) v.x += GDOT((R),(O)); v.y += GDOT((R)+1,(O)); v.z += GDOT((R)+2,(O)); v.w += GDOT((R)+3,(O));
#define HV4(v, R)     v.x = fmaxf(Bv[(R)]+XDOT(W4,(R),8,0),0.f); v.y = fmaxf(Bv[(R)+1]+XDOT(W4,(R)+1,8,0),0.f); \
                      v.z = fmaxf(Bv[(R)+2]+XDOT(W4,(R)+2,8,0),0.f); v.w = fmaxf(Bv[(R)+3]+XDOT(W4,(R)+3,8,0),0.f);
#define REDCH(v, OFF) do { \
  float4 mx = act ? (v) : make_float4(-__builtin_inff(),-__builtin_inff(),-__builtin_inff(),-__builtin_inff()); \
  float4 sv = act ? (v) : make_float4(0.f,0.f,0.f,0.f); \
  mx = f4max(mx, shfl4(mx,32)); sv = f4add(sv, shfl4(sv,32)); \
  mx = f4max(mx, shfl4(mx,16)); sv = f4add(sv, shfl4(sv,16)); \
  mx = f4max(mx, shfl4(mx, 8)); sv = f4add(sv, shfl4(sv, 8)); \
  mx = f4max(mx, shfl4(mx, 4)); sv = f4add(sv, shfl4(sv, 4)); \
  mx = f4max(mx, shfl4(mx, 2)); sv = f4add(sv, shfl4(sv, 2)); \
  mx = f4max(mx, shfl4(mx, 1)); sv = f4add(sv, shfl4(sv, 1)); \
  if (lane == 0) { *((float4*)(sm.redm + wv*32 + (OFF))) = mx; *((float4*)(sm.reds + wv*32 + (OFF))) = sv; } \
} while (0)

extern "C" __global__ void
__attribute__((amdgpu_flat_work_group_size(1024,1024)))
__attribute__((amdgpu_waves_per_eu(4,4)))
gnn_topk_kernel(const int* __restrict__ x_ids, const int* __restrict__ eidx,
                const float* __restrict__ emb,
                const float* __restrict__ w1, const float* __restrict__ b1,
                const float* __restrict__ u1, const float* __restrict__ p1,
                const float* __restrict__ w2, const float* __restrict__ b2,
                const float* __restrict__ u2, const float* __restrict__ p2,
                const float* __restrict__ w3, const float* __restrict__ b3,
                const float* __restrict__ u3, const float* __restrict__ p3,
                const float* __restrict__ l1w, const float* __restrict__ l1b,
                const float* __restrict__ l2w, const float* __restrict__ l2b,
                const float* __restrict__ l3w, const float* __restrict__ l3b,
                float* __restrict__ out)
{
  const int g = blockIdx.x;
  const int tid = (int)threadIdx.x;
  const int lane = tid & 63, wv = tid >> 6;

  __shared__ Smem sm;
  unsigned short* hb = sm.hu.h;

  const int* esrc = eidx + (size_t)g * (2 * NEDGE);
  const int* edst = esrc + NEDGE;

  // ---- init: x = emb[ids]; nodes never move between threads ----
  float4 x0,x1,x2,x3,x4,x5,x6,x7;
  bool alive = (tid < NNODE);
  if (alive) {
    int id = x_ids[(size_t)g * NNODE + tid];
    const float4* ep = (const float4*)(emb + id * DIM);
    x0=ep[0]; x1=ep[1]; x2=ep[2]; x3=ep[3]; x4=ep[4]; x5=ep[5]; x6=ep[6]; x7=ep[7];
  } else {
    x0=x1=x2=x3=x4=x5=x6=x7=make_float4(0.f,0.f,0.f,0.f);
  }
  sm.alv[tid] = alive ? 1 : 0;
  if (tid < 64) sm.eacc[tid] = 0.f;
  __syncthreads();

  unsigned wbeg = 0, wend = 0;

  #pragma unroll 1
  for (int layer = 0; layer < 3; ++layer) {
    const float* W  = (layer==0)? w1 : (layer==1)? w2 : w3;
    const float* Bv = (layer==0)? b1 : (layer==1)? b2 : b3;
    const float* U  = (layer==0)? u1 : (layer==1)? u2 : u3;
    const float* P  = (layer==0)? p1 : (layer==1)? p2 : p3;
    const int k     = (layer==0)? 800 : (layer==1)? 640 : 512;
    const float4* W4 = (const float4*)W;
    const float4* U4 = (const float4*)U;

    if (layer == 0) {
      // ---- CSR build ONCE: buckets by original dst id ----
      sm.cnt[tid] = 0u;
      __syncthreads();
      for (int e = tid; e < NEDGE; e += 1024) {
        int s = esrc[e];
        int d = edst[e];
        atomicAdd(&sm.cnt[d], 1u);
        sm.hu.stage[e] = ((unsigned)d << 16) | (unsigned)s;
      }
      __syncthreads();
      unsigned cv = sm.cnt[tid];
      unsigned excl = blockExclScan(cv, sm.wsum, tid);
      unsigned total = sm.wsum[15];
      if (tid < NNODE) sm.rowStart[tid] = excl;
      if (tid == 0) sm.rowStart[NNODE] = total;
      sm.cnt[tid] = excl;              // cursor
      __syncthreads();
      for (int e = tid; e < NEDGE; e += 1024) {
        unsigned pk = sm.hu.stage[e];
        unsigned d = pk >> 16;
        unsigned pos = atomicAdd(&sm.cnt[d], 1u);
        sm.csr[pos] = (unsigned short)(pk & 0xFFFFu);
      }
      __syncthreads();   // stage consumed; h region reusable
      if (tid < NNODE) { wbeg = sm.rowStart[tid]; wend = sm.rowStart[tid + 1]; }
    } else {
      // ---- compact own bucket: drop edges from dead srcs (race-free: own region) ----
      if (alive) {
        unsigned w = wbeg;
        for (unsigned e = wbeg; e < wend; ++e) {
          unsigned short s = sm.csr[e];
          if (sm.alv[s]) sm.csr[w++] = s;
        }
        wend = w;
      }
    }

    uint4* hq = (uint4*)(hb + tid * HSU);

    // ---- phase 1: full h = relu(W@x+b), packed bf16 -> own row; then a = U2@x ----
    float4 a0,a1,a2,a3,a4,a5,a6,a7;
    if (alive) {
      float4 t0, t1; uint4 q;
      HV4(t0,0)  HV4(t1,4)  CVTQ(q,t0,t1); hq[0]=q;
      HV4(t0,8)  HV4(t1,12) CVTQ(q,t0,t1); hq[1]=q;
      HV4(t0,16) HV4(t1,20) CVTQ(q,t0,t1); hq[2]=q;
      HV4(t0,24) HV4(t1,28) CVTQ(q,t0,t1); hq[3]=q;
      ACC4(a0,0) ACC4(a1,4) ACC4(a2,8) ACC4(a3,12)
      ACC4(a4,16) ACC4(a5,20) ACC4(a6,24) ACC4(a7,28)
    }
    __syncthreads();   // all packed rows visible; x dead from here

    // ---- single walk: packed u16-max over all 32 features (branch-free, alive srcs only) ----
    if (alive) {
      uint4 g0 = hq[0], g1 = hq[1], g2 = hq[2], g3 = hq[3];   // self-loop init
      for (unsigned e = wbeg; e < wend; ++e) {
        const uint4* rp = (const uint4*)(hb + sm.csr[e] * HSU);
        uint4 v0 = rp[0], v1 = rp[1], v2 = rp[2], v3 = rp[3];
        PKM(g0.x,v0.x); PKM(g0.y,v0.y); PKM(g0.z,v0.z); PKM(g0.w,v0.w);
        PKM(g1.x,v1.x); PKM(g1.y,v1.y); PKM(g1.z,v1.z); PKM(g1.w,v1.w);
        PKM(g2.x,v2.x); PKM(g2.y,v2.y); PKM(g2.z,v2.z); PKM(g2.w,v2.w);
        PKM(g3.x,v3.x); PKM(g3.y,v3.y); PKM(g3.z,v3.z); PKM(g3.w,v3.w);
      }
      float4 h0,h1,h2,h3;
      EXPAND(h0,h1,g0); EXPAND(h2,h3,g1);
      ACC4ADD(a0,0,0) ACC4ADD(a1,4,0) ACC4ADD(a2,8,0) ACC4ADD(a3,12,0)
      ACC4ADD(a4,16,0) ACC4ADD(a5,20,0) ACC4ADD(a6,24,0) ACC4ADD(a7,28,0)
      EXPAND(h0,h1,g2); EXPAND(h2,h3,g3);
      ACC4ADD(a0,0,4) ACC4ADD(a1,4,4) ACC4ADD(a2,8,4) ACC4ADD(a3,12,4)
      ACC4ADD(a4,16,4) ACC4ADD(a5,20,4) ACC4ADD(a6,24,4) ACC4ADD(a7,28,4)
      x0=f4relu(a0); x1=f4relu(a1); x2=f4relu(a2); x3=f4relu(a3);
      x4=f4relu(a4); x5=f4relu(a5); x6=f4relu(a6); x7=f4relu(a7);
    }

    // ---- pool: score = tanh(x.p/||p||) (kept in register) ----
    float pn = 0.f;
    for (int c = 0; c < DIM; ++c) pn += P[c] * P[c];
    pn = sqrtf(pn);
    const float4* P4 = (const float4*)P;
    unsigned key = 0xFFFFFFFFu;
    float val = 0.f;
    if (alive) {
      float dp = dot4(P4[0],x0)+dot4(P4[1],x1)+dot4(P4[2],x2)+dot4(P4[3],x3)
               + dot4(P4[4],x4)+dot4(P4[5],x5)+dot4(P4[6],x6)+dot4(P4[7],x7);
      val = tanhf(dp / pn);
      key = ~monof(val);   // ascending key == descending score
    }
    for (int i = tid; i < 257; i += 1024) { sm.histA[i] = 0u; sm.histB[i] = 0u; }
    __syncthreads();   // all walk reads complete before rows rewritten next layer

    // ---- exact top-k: 4-pass radix select, ping-pong histograms ----
    bool cand = alive;
    bool sel = false;
    unsigned target = (unsigned)k;
    unsigned dig = (key >> 24) & 255u;
    if (cand) atomicAdd(&sm.histA[dig], 1u);
    __syncthreads();
    #pragma unroll 1
    for (int p = 0; p < 4; ++p) {
      unsigned* buf  = (p & 1) ? sm.histB : sm.histA;
      unsigned* nbuf = (p & 1) ? sm.histA : sm.histB;
      if (tid < 64) {   // wave0: exclusive scan of 256 bins
        unsigned q0 = buf[tid*4], q1 = buf[tid*4+1], q2 = buf[tid*4+2], q3 = buf[tid*4+3];
        unsigned s1 = q0+q1, s2v = s1+q2, s3 = s2v+q3;
        unsigned tot = s3;
        #pragma unroll
        for (int d = 1; d < 64; d <<= 1) {
          unsigned t = __shfl_up(tot, d, 64);
          if (lane >= d) tot += t;
        }
        unsigned base = tot - s3;
        buf[tid*4] = base; buf[tid*4+1] = base+q0; buf[tid*4+2] = base+s1; buf[tid*4+3] = base+s2v;
        if (tid == 63) buf[256] = tot;
      } else if (p > 0 && p < 3) {
        for (int i = tid - 64; i < 257; i += 960) nbuf[i] = 0u;
      }
      __syncthreads();
      if (cand) {
        unsigned lo = buf[dig], hi = buf[dig+1];
        if (hi <= target)      { sel = true;  cand = false; }
        else if (lo >= target) { cand = false; }
        else                   { target -= lo; }
      }
      if (p < 3) {
        dig = (key >> (16 - 8*p)) & 255u;
        if (cand) atomicAdd(&nbuf[dig], 1u);
      }
      __syncthreads();
    }
    // tie resolution: ballot-based rank (smallest original tid wins)
    {
      unsigned long long bm = __ballot(cand);
      if (lane == 0) sm.wsum[wv] = (unsigned)__popcll(bm);
      __syncthreads();
      unsigned pre = 0;
      for (int w_ = 0; w_ < wv; ++w_) pre += sm.wsum[w_];
      unsigned trank = pre + (unsigned)__popcll(bm & ((1ULL << lane) - 1ULL));
      if (cand && trank < target) sel = true;
    }

    // ---- select-in-place ----
    alive = sel;
    sm.alv[tid] = sel ? 1 : 0;   // read by next layer's compaction (after readout barrier)
    if (sel) {
      x0=f4scale(x0,val); x1=f4scale(x1,val); x2=f4scale(x2,val); x3=f4scale(x3,val);
      x4=f4scale(x4,val); x5=f4scale(x5,val); x6=f4scale(x6,val); x7=f4scale(x7,val);
    } else {
      x0=x1=x2=x3=x4=x5=x6=x7=make_float4(0.f,0.f,0.f,0.f);
    }

    // ---- readout: gmp || gap over survivors ----
    {
      bool act = alive;
      REDCH(x0, 0); REDCH(x1, 4); REDCH(x2, 8);  REDCH(x3, 12);
      REDCH(x4,16); REDCH(x5,20); REDCH(x6,24);  REDCH(x7,28);
    }
    __syncthreads();
    if (tid < 32) {
      float rm = -__builtin_inff(), rs = 0.f;
      #pragma unroll
      for (int w_ = 0; w_ < 16; ++w_) {
        rm = fmaxf(rm, sm.redm[w_*32 + tid]);
        rs += sm.reds[w_*32 + tid];
      }
      sm.eacc[tid] += rm;
      sm.eacc[32 + tid] += rs / (float)k;
    }
    __syncthreads();
  }

  // ---- MLP head ----
  if (tid < 32) {
    float v = l1b[tid];
    #pragma unroll
    for (int c = 0; c < 64; ++c) v += l1w[tid*64 + c] * sm.eacc[c];
    sm.hbuf[tid] = fmaxf(v, 0.f);
  }
  __syncthreads();
  if (tid < 16) {
    float v = l2b[tid];
    #pragma unroll
    for (int c = 0; c < 32; ++c) v += l2w[tid*32 + c] * sm.hbuf[c];
    sm.hbuf[32 + tid] = fmaxf(v, 0.f);
  }
  __syncthreads();
  if (tid == 0) {
    float v = l3b[0];
    #pragma unroll
    for (int c = 0; c < 16; ++c) v += l3w[c] * sm.hbuf[32 + c];
    out[g] = 1.f / (1.f + expf(-v));
  }
  if (tid < 64) out[NGRAPH + (size_t)g*64 + tid] = sm.eacc[tid];
}

extern "C" void kernel_launch(void* const* d_in, const int* in_sizes, int n_in,
                              void* d_out, int out_size, void* d_ws, size_t ws_size,
                              hipStream_t stream) {
  (void)in_sizes; (void)n_in; (void)d_ws; (void)ws_size; (void)out_size;
  const int*   x_ids = (const int*)d_in[0];
  const int*   eidx  = (const int*)d_in[1];
  const float* emb   = (const float*)d_in[2];
  const float* w1 = (const float*)d_in[3],  *b1 = (const float*)d_in[4];
  const float* u1 = (const float*)d_in[5],  *p1 = (const float*)d_in[6];
  const float* w2 = (const float*)d_in[7],  *b2 = (const float*)d_in[8];
  const float* u2 = (const float*)d_in[9],  *p2 = (const float*)d_in[10];
  const float* w3 = (const float*)d_in[11], *b3 = (const float*)d_in[12];
  const float* u3 = (const float*)d_in[13], *p3 = (const float*)d_in[14];
  const float* l1w = (const float*)d_in[15], *l1b = (const float*)d_in[16];
  const float* l2w = (const float*)d_in[17], *l2b = (const float*)d_in[18];
  const float* l3w = (const float*)d_in[19], *l3b = (const float*)d_in[20];
  float* out = (float*)d_out;

  gnn_topk_kernel<<<dim3(NGRAPH), dim3(1024), 0, stream>>>(
      x_ids, eidx, emb,
      w1, b1, u1, p1, w2, b2, u2, p2, w3, b3, u3, p3,
      l1w, l1b, l2w, l2b, l3w, l3b, out);
}